// Round 1
// baseline (691.879 us; speedup 1.0000x reference)
//
#include <hip/hip_runtime.h>

// Problem constants
constexpr int TT = 512;    // timesteps
constexpr int BB = 256;    // batch
constexpr int HH = 128;    // hidden = embed
constexpr int VV = 32000;  // vocab

typedef _Float16 h2 __attribute__((ext_vector_type(2)));

struct H8x { h2 a, b, c, d; };  // 16B chunk of LDS comb (8 fp16)

__device__ __forceinline__ float fdot2(h2 x, h2 y, float c) {
#if __has_builtin(__builtin_amdgcn_fdot2)
  return __builtin_amdgcn_fdot2(x, y, c, false);
#else
  return c + (float)x[0] * (float)y[0] + (float)x[1] * (float)y[1];
#endif
}

__device__ __forceinline__ float fsigmoid(float x) {
  return 1.f / (1.f + __expf(-x));
}
__device__ __forceinline__ float ftanh(float x) {
  return 1.f - 2.f / (__expf(2.f * x) + 1.f);
}

// One block per batch element; 512 threads = 4 gates x 128 units.
// Thread j (g = j>>7, u = j&127) holds the full 256-row weight column
// W_g[:, u] as 128 packed fp16 pairs in VGPRs for the whole time loop.
__global__ __launch_bounds__(512, 2) void lstm_rec(
    const int* __restrict__ x, const float* __restrict__ emb,
    const float* __restrict__ Wi, const float* __restrict__ bi,
    const float* __restrict__ Wf, const float* __restrict__ bf,
    const float* __restrict__ Wc, const float* __restrict__ bc,
    const float* __restrict__ Wo, const float* __restrict__ bo,
    float* __restrict__ hout) {
  const int b = blockIdx.x;
  const int tid = threadIdx.x;
  const int g = tid >> 7;
  const int u = tid & 127;

  __shared__ int xrow[TT];
  __shared__ __align__(16) h2 comb2[128];  // 256 fp16: [0..127]=e_t, [128..255]=h
  __shared__ float gates[512];

  const float* Wg = (g == 0) ? Wi : (g == 1) ? Wf : (g == 2) ? Wc : Wo;
  const float* bg = (g == 0) ? bi : (g == 1) ? bf : (g == 2) ? bc : bo;

  xrow[tid] = x[b * TT + tid];

  // Pack weight column into 128 VGPRs of fp16 pairs.
  h2 wreg[128];
#pragma unroll
  for (int k2 = 0; k2 < 128; ++k2) {
    float w0 = Wg[(2 * k2) * HH + u];
    float w1 = Wg[(2 * k2 + 1) * HH + u];
    wreg[k2] = h2{(_Float16)w0, (_Float16)w1};
  }
  const float bias = bg[u];

  __syncthreads();  // xrow visible

  float c_reg = 0.f;
  float e_pref = 0.f;
  if (tid < 128) {
    float e0 = emb[(size_t)xrow[0] * HH + u];
    _Float16* ch = (_Float16*)comb2;
    ch[u] = (_Float16)e0;
    ch[128 + u] = (_Float16)0.f;
  }
  __syncthreads();

  for (int t = 0; t < TT; ++t) {
    // Prefetch next timestep's embedding row (consumed after the barrier).
    if (tid < 128) {
      int tn = (t + 1 < TT) ? t + 1 : t;
      e_pref = emb[(size_t)xrow[tn] * HH + u];
    }

    // pre-activation = dot(comb, W_col) + bias ; comb read as LDS broadcasts.
    float a0 = 0.f, a1 = 0.f, a2 = 0.f, a3 = 0.f;
    const H8x* c8 = (const H8x*)comb2;
#pragma unroll
    for (int k8 = 0; k8 < 32; ++k8) {
      H8x cc = c8[k8];
      a0 = fdot2(cc.a, wreg[4 * k8 + 0], a0);
      a1 = fdot2(cc.b, wreg[4 * k8 + 1], a1);
      a2 = fdot2(cc.c, wreg[4 * k8 + 2], a2);
      a3 = fdot2(cc.d, wreg[4 * k8 + 3], a3);
    }
    float pre = ((a0 + a1) + (a2 + a3)) + bias;
    float act = (g == 2) ? ftanh(pre) : fsigmoid(pre);
    gates[tid] = act;
    __syncthreads();

    if (tid < 128) {
      float gi = gates[u];
      float gf = gates[128 + u];
      float gc = gates[256 + u];
      float go = gates[384 + u];
      c_reg = gf * c_reg + gi * gc;
      float hv = go * ftanh(c_reg);
      _Float16* ch = (_Float16*)comb2;
      ch[128 + u] = (_Float16)hv;
      ch[u] = (_Float16)e_pref;
      if (t == TT - 1) hout[b * HH + u] = hv;
    }
    __syncthreads();
  }
}

// logits[b][v] = dot(h[b], Wout[:,v]) + bout[v]
// 250 blocks x 256 threads; thread handles one v column (Wout col in VGPRs),
// h staged in LDS 64-batch-row chunks, broadcast reads.
__global__ __launch_bounds__(256, 1) void lstm_out(
    const float* __restrict__ hin, const float* __restrict__ Wout,
    const float* __restrict__ bout, float* __restrict__ out) {
  const int tid = threadIdx.x;
  const int v = blockIdx.x * 128 + (tid & 127);
  const int bh = tid >> 7;  // which 32-row half of the staged chunk

  __shared__ __align__(16) float hs[64 * HH];  // 32 KB

  float w[128];
#pragma unroll
  for (int k = 0; k < HH; ++k) w[k] = Wout[k * VV + v];
  const float bv = bout[v];

  for (int c = 0; c < 4; ++c) {
    __syncthreads();  // protect hs reuse across chunks
    const float4* src = (const float4*)(hin + (size_t)c * 64 * HH);
    float4* dst = (float4*)hs;
#pragma unroll
    for (int i = 0; i < 8; ++i) dst[i * 256 + tid] = src[i * 256 + tid];
    __syncthreads();

#pragma unroll 1
    for (int bb = 0; bb < 32; ++bb) {
      int br = bh * 32 + bb;
      float acc = bv;
      const float4* hr = (const float4*)(hs + br * HH);
#pragma unroll
      for (int k4 = 0; k4 < 32; ++k4) {
        float4 hh = hr[k4];
        acc += hh.x * w[4 * k4 + 0];
        acc += hh.y * w[4 * k4 + 1];
        acc += hh.z * w[4 * k4 + 2];
        acc += hh.w * w[4 * k4 + 3];
      }
      out[(size_t)(c * 64 + br) * VV + v] = acc;
    }
  }
}

extern "C" void kernel_launch(void* const* d_in, const int* in_sizes, int n_in,
                              void* d_out, int out_size, void* d_ws,
                              size_t ws_size, hipStream_t stream) {
  const int* x = (const int*)d_in[0];
  const float* emb = (const float*)d_in[1];
  const float* Wi = (const float*)d_in[2];
  const float* bi = (const float*)d_in[3];
  const float* Wf = (const float*)d_in[4];
  const float* bf = (const float*)d_in[5];
  const float* Wc = (const float*)d_in[6];
  const float* bc = (const float*)d_in[7];
  const float* Wo = (const float*)d_in[8];
  const float* bo = (const float*)d_in[9];
  const float* Wout = (const float*)d_in[10];
  const float* bout = (const float*)d_in[11];
  float* out = (float*)d_out;
  float* hbuf = (float*)d_ws;  // 256*128 fp32 final hidden state

  lstm_rec<<<BB, 512, 0, stream>>>(x, emb, Wi, bi, Wf, bf, Wc, bc, Wo, bo,
                                   hbuf);
  lstm_out<<<VV / 128, 256, 0, stream>>>(hbuf, Wout, bout, out);
}

// Round 3
// 676.550 us; speedup vs baseline: 1.0227x; 1.0227x over previous
//
#include <hip/hip_runtime.h>

constexpr int TT = 512;    // timesteps
constexpr int BB = 256;    // batch
constexpr int HH = 128;    // hidden = embed
constexpr int VV = 32000;  // vocab

typedef _Float16 h2 __attribute__((ext_vector_type(2)));
typedef _Float16 f16x8 __attribute__((ext_vector_type(8)));
typedef float f32x4 __attribute__((ext_vector_type(4)));

struct __align__(8) H2x2 { h2 x, y; };
struct __align__(16) H2x4 { h2 a, b, c, d; };

__device__ __forceinline__ h2 pkrtz(float a, float b) {
  return __builtin_bit_cast(h2, __builtin_amdgcn_cvt_pkrtz(a, b));
}
__device__ __forceinline__ float fdot2(h2 a, h2 b, float c) {
  return __builtin_amdgcn_fdot2(a, b, c, false);
}
__device__ __forceinline__ float fsigmoid(float x) {
  return 1.f / (1.f + __expf(-x));
}
__device__ __forceinline__ float ftanh(float x) {
  return 1.f - 2.f / (__expf(2.f * x) + 1.f);
}

// One block per batch element, 1024 threads = 16 waves.
// k-split R=16: wave w owns k in [w*16, w*16+16). Thread (w,l) computes 8
// partial pre-activations: the 4 gates (i,f,c,o) for units 2l and 2l+1,
// over its 16-wide k slice. Weights live in 64 VGPRs of packed fp16 pairs;
// comb read = 32 B/thread (vs 512 B in the broadcast version).
// Partials go to LDS as packed fp16 (one b128/thread, conflict-free);
// reducer thread u extracts them with v_dot2 against (1,0)/(0,1) so the
// 16-way sum accumulates in fp32, then does the c/h update in-place.
__global__ __launch_bounds__(1024, 4) void lstm_rec(
    const int* __restrict__ x, const float* __restrict__ emb,
    const float* __restrict__ Wi, const float* __restrict__ bi,
    const float* __restrict__ Wf, const float* __restrict__ bf,
    const float* __restrict__ Wc, const float* __restrict__ bc,
    const float* __restrict__ Wo, const float* __restrict__ bo,
    _Float16* __restrict__ hbf) {
  const int b = blockIdx.x;
  const int tid = threadIdx.x;
  const int w = tid >> 6;
  const int l = tid & 63;

  __shared__ int xrow[TT];
  __shared__ __align__(16) h2 comb2[128];        // fp16[256]: [0,128)=e, [128,256)=h
  __shared__ __align__(16) H2x2 part[16 * 128];  // [w][u] gate-quad partials

  // ---- weight columns into VGPRs (one-time) ----
  const float* Wp[4] = {Wi, Wf, Wc, Wo};
  h2 wl[8][8];
#pragma unroll
  for (int j = 0; j < 8; ++j) {
    const float* Wg = Wp[j & 3];
    const int col = 2 * l + (j >> 2);
#pragma unroll
    for (int i = 0; i < 8; ++i) {
      const int k = w * 16 + 2 * i;
      wl[j][i] = h2{(_Float16)Wg[k * HH + col], (_Float16)Wg[(k + 1) * HH + col]};
    }
  }

  if (tid < TT) xrow[tid] = x[b * TT + tid];

  const bool is_red = (tid < 256) && ((tid & 32) == 0);  // waves 0-3, lanes 0-31
  const int u = (tid >> 6) * 32 + (tid & 31);            // unit id for reducers
  float c_state = 0.f;
  float4 bias4 = {0.f, 0.f, 0.f, 0.f};
  if (is_red) bias4 = {bi[u], bf[u], bc[u], bo[u]};

  const bool is_el = (tid >= 256 && tid < 384);  // waves 4-5: e prefetchers
  const int ue = tid - 256;
  float e_next = 0.f;

  __syncthreads();  // xrow visible

  if (tid < 128) {
    float e0 = emb[(size_t)xrow[0] * HH + tid];
    ((_Float16*)comb2)[tid] = (_Float16)e0;
    ((_Float16*)comb2)[128 + tid] = (_Float16)0.f;
  }
  if (is_el) e_next = emb[(size_t)xrow[1] * HH + ue];
  __syncthreads();

  const h2 LO = h2{(_Float16)1.f, (_Float16)0.f};
  const h2 HI = h2{(_Float16)0.f, (_Float16)1.f};

  for (int t = 0; t < TT; ++t) {
    // ---- phase 1: all threads, partial dots over k slice ----
    H2x4 ca = ((const H2x4*)comb2)[w * 2];
    H2x4 cb = ((const H2x4*)comb2)[w * 2 + 1];
    h2 cc[8] = {ca.a, ca.b, ca.c, ca.d, cb.a, cb.b, cb.c, cb.d};
    float p[8];
#pragma unroll
    for (int j = 0; j < 8; ++j) {
      float s = 0.f;
#pragma unroll
      for (int i = 0; i < 8; ++i) s = fdot2(cc[i], wl[j][i], s);
      p[j] = s;
    }
    H2x4 q;
    q.a = pkrtz(p[0], p[1]);  // (i,f) of unit 2l
    q.b = pkrtz(p[2], p[3]);  // (c,o) of unit 2l
    q.c = pkrtz(p[4], p[5]);  // (i,f) of unit 2l+1
    q.d = pkrtz(p[6], p[7]);  // (c,o) of unit 2l+1
    ((H2x4*)part)[w * 64 + l] = q;  // contiguous 16B/lane
    __syncthreads();

    // ---- phase 2: reduce + activate + state update (128 threads) ----
    if (is_red) {
      float ai = 0.f, af = 0.f, ac = 0.f, ao = 0.f;
#pragma unroll
      for (int ww = 0; ww < 16; ++ww) {
        H2x2 pp = part[ww * 128 + u];  // b64, contiguous per lane
        ai = fdot2(pp.x, LO, ai);
        af = fdot2(pp.x, HI, af);
        ac = fdot2(pp.y, LO, ac);
        ao = fdot2(pp.y, HI, ao);
      }
      float gi = fsigmoid(ai + bias4.x);
      float gf = fsigmoid(af + bias4.y);
      float gc = ftanh(ac + bias4.z);
      float go = fsigmoid(ao + bias4.w);
      c_state = gf * c_state + gi * gc;
      float hv = go * ftanh(c_state);
      ((_Float16*)comb2)[128 + u] = (_Float16)hv;
      if (t == TT - 1) hbf[b * HH + u] = (_Float16)hv;
    } else if (is_el) {
      ((_Float16*)comb2)[ue] = (_Float16)e_next;  // e_{t+1}
      int t2 = (t + 2 < TT) ? t + 2 : TT - 1;
      e_next = emb[(size_t)xrow[t2] * HH + ue];   // prefetch e_{t+2}
    }
    __syncthreads();
  }
}

// Wout[k][v] fp32 -> Wt[v][k] fp16 (coalesced loads across lanes=v,
// 16B row-chunk stores).
__global__ __launch_bounds__(256, 4) void wout_tr(const float* __restrict__ Wout,
                                                  _Float16* __restrict__ Wt) {
  const int v = blockIdx.x * 256 + threadIdx.x;
#pragma unroll 1
  for (int kc = 0; kc < 16; ++kc) {
    float f[8];
#pragma unroll
    for (int i = 0; i < 8; ++i) f[i] = Wout[(size_t)(kc * 8 + i) * VV + v];
    H2x4 q;
    q.a = pkrtz(f[0], f[1]);
    q.b = pkrtz(f[2], f[3]);
    q.c = pkrtz(f[4], f[5]);
    q.d = pkrtz(f[6], f[7]);
    *(H2x4*)(Wt + (size_t)v * HH + kc * 8) = q;
  }
}

// logits = h @ Wout + bout via f16 MFMA, register-only (no LDS).
// Block: 256 thr = 4 waves; tile [64 bat x 128 v]; wave: [64 bat x 32 v].
// A[m=lane&15][k=quad*8+j] = hbf row; B[k][n=lane&15] = Wt row (Wout^T).
// C/D: col=lane&15 (v), row=quad*4+reg (bat).
__global__ __launch_bounds__(256, 4) void lstm_out(
    const _Float16* __restrict__ Wt, const _Float16* __restrict__ hbf,
    const float* __restrict__ bout, float* __restrict__ out) {
  const int tid = threadIdx.x;
  const int wv = tid >> 6;
  const int lane = tid & 63;
  const int vblk = blockIdx.x % 250;
  const int batblk = blockIdx.x / 250;
  const int n16 = lane & 15;
  const int quad = lane >> 4;
  const int vbase = vblk * 128 + wv * 32;
  const int batbase = batblk * 64;

  f32x4 acc[4][2] = {};
#pragma unroll
  for (int ks = 0; ks < 4; ++ks) {
    const int k = ks * 32 + quad * 8;
    f16x8 a[4], bf_[2];
#pragma unroll
    for (int mt = 0; mt < 4; ++mt)
      a[mt] = *(const f16x8*)(hbf + (size_t)(batbase + mt * 16 + n16) * HH + k);
#pragma unroll
    for (int vt = 0; vt < 2; ++vt)
      bf_[vt] = *(const f16x8*)(Wt + (size_t)(vbase + vt * 16 + n16) * HH + k);
#pragma unroll
    for (int mt = 0; mt < 4; ++mt)
#pragma unroll
      for (int vt = 0; vt < 2; ++vt)
        acc[mt][vt] = __builtin_amdgcn_mfma_f32_16x16x32_f16(a[mt], bf_[vt],
                                                             acc[mt][vt], 0, 0, 0);
  }
#pragma unroll
  for (int vt = 0; vt < 2; ++vt) {
    const int v = vbase + vt * 16 + n16;
    const float bv = bout[v];
#pragma unroll
    for (int mt = 0; mt < 4; ++mt) {
#pragma unroll
      for (int r = 0; r < 4; ++r) {
        const int bat = batbase + mt * 16 + quad * 4 + r;
        out[(size_t)bat * VV + v] = acc[mt][vt][r] + bv;
      }
    }
  }
}

extern "C" void kernel_launch(void* const* d_in, const int* in_sizes, int n_in,
                              void* d_out, int out_size, void* d_ws,
                              size_t ws_size, hipStream_t stream) {
  const int* x = (const int*)d_in[0];
  const float* emb = (const float*)d_in[1];
  const float* Wi = (const float*)d_in[2];
  const float* bi = (const float*)d_in[3];
  const float* Wf = (const float*)d_in[4];
  const float* bf = (const float*)d_in[5];
  const float* Wc = (const float*)d_in[6];
  const float* bc = (const float*)d_in[7];
  const float* Wo = (const float*)d_in[8];
  const float* bo = (const float*)d_in[9];
  const float* Wout = (const float*)d_in[10];
  const float* bout = (const float*)d_in[11];
  float* out = (float*)d_out;

  _Float16* Wt = (_Float16*)d_ws;        // 32000*128 fp16 = 8.192 MB
  _Float16* hbf = Wt + (size_t)VV * HH;  // 256*128 fp16 = 64 KB

  wout_tr<<<VV / 256, 256, 0, stream>>>(Wout, Wt);
  lstm_rec<<<BB, 1024, 0, stream>>>(x, emb, Wi, bi, Wf, bf, Wc, bc, Wo, bo, hbf);
  lstm_out<<<(VV / 128) * (BB / 64), 256, 0, stream>>>(Wt, hbf, bout, out);
}